// Round 2
// baseline (2972.422 us; speedup 1.0000x reference)
//
#include <hip/hip_runtime.h>
#include <hip/hip_bf16.h>

typedef __attribute__((ext_vector_type(8))) short bf16x8;
typedef __attribute__((ext_vector_type(4))) float f32x4;

#define N_ROWS 32768
#define K_KEYS 4096
#define DDIM   1024
#define BM 32
#define BK 128
#define NBLK (K_KEYS / BK)   /* 32 */
#define SPITCH 132           /* fp32 pad */

__device__ __forceinline__ ushort f2bf(float f) {
    __hip_bfloat16 b = __float2bfloat16(f);
    return *(ushort*)&b;
}
__device__ __forceinline__ float bf2f(ushort u) {
    __hip_bfloat16 b = *(__hip_bfloat16*)&u;
    return __bfloat162float(b);
}

// swizzled LDS index helpers (ushort units; XOR 16B-granule with row&7)
__device__ __forceinline__ int qidx(int r, int c_us) { return r * 1024 + (c_us ^ ((r & 7) << 3)); }
__device__ __forceinline__ int pidx(int r, int c_us) { return r * 128  + (c_us ^ ((r & 7) << 3)); }

// barrier that does NOT drain vmcnt (global prefetches stay in flight);
// all cross-wave deps in the K-loop are LDS-only, so lgkmcnt(0) suffices.
__device__ __forceinline__ void barrier_lgkm() {
    asm volatile("s_waitcnt lgkmcnt(0)" ::: "memory");
    __builtin_amdgcn_s_barrier();
    asm volatile("" ::: "memory");
}

// keys fp32 -> hi/lo bf16 split (residual split: hi = rne(f), lo = rne(f - hi))
__global__ void prep_split(const float* __restrict__ src,
                           ushort* __restrict__ hi,
                           ushort* __restrict__ lo) {
    const int total4 = K_KEYS * DDIM / 4;
    int stride = gridDim.x * blockDim.x;
    for (int i = blockIdx.x * blockDim.x + threadIdx.x; i < total4; i += stride) {
        float4 v = ((const float4*)src)[i];
        float f[4] = {v.x, v.y, v.z, v.w};
        ushort h[4], l[4];
#pragma unroll
        for (int j = 0; j < 4; j++) {
            h[j] = f2bf(f[j]);
            l[j] = f2bf(f[j] - bf2f(h[j]));
        }
        ((ushort4*)hi)[i] = make_ushort4(h[0], h[1], h[2], h[3]);
        ((ushort4*)lo)[i] = make_ushort4(l[0], l[1], l[2], l[3]);
    }
}

// values fp32 [K][D] -> vt bf16 [D][K]
__global__ void prep_vt(const float* __restrict__ v, ushort* __restrict__ vt) {
    __shared__ float tile[32][33];
    const int tk = blockIdx.x;
    const int td = blockIdx.y;
    const int tx = threadIdx.x;
    const int ty = threadIdx.y;
#pragma unroll
    for (int r = 0; r < 4; r++) {
        int k = tk * 32 + ty + 8 * r;
        tile[ty + 8 * r][tx] = v[(size_t)k * DDIM + td * 32 + tx];
    }
    __syncthreads();
#pragma unroll
    for (int r = 0; r < 4; r++) {
        int d = td * 32 + ty + 8 * r;
        vt[(size_t)d * K_KEYS + tk * 32 + tx] = f2bf(tile[tx][ty + 8 * r]);
    }
}

__launch_bounds__(512, 2)
__global__ void attn_main(const float* __restrict__ z,
                          const ushort* __restrict__ kh,
                          const ushort* __restrict__ kl,
                          const ushort* __restrict__ vt,
                          float* __restrict__ out) {
    __shared__ ushort Qh[BM * 1024];          // swizzled, pitch 1024
    __shared__ ushort Ql[BM * 1024];
    __shared__ float  Ssc[BM][SPITCH];
    __shared__ ushort Pt[BM * 128];           // swizzled, pitch 128
    __shared__ float  m_s[BM], l_s[BM], sc_s[BM];

    const int tid  = threadIdx.x;
    const int wave = tid >> 6;
    const int lane = tid & 63;
    const int l16  = lane & 15;
    const int lq   = lane >> 4;       // 0..3
    const int row0 = blockIdx.x * BM;

    // ---- load z rows -> Qh/Ql (split-bf16, swizzled stores) ----
#pragma unroll
    for (int j = 0; j < 16; j++) {
        int idx = j * 512 + tid;           // float4 index in [32][256]
        int r   = idx >> 8;
        int c4  = idx & 255;
        float4 v = ((const float4*)(z + (size_t)(row0 + r) * DDIM))[c4];
        float f[4] = {v.x, v.y, v.z, v.w};
        ushort h[4], l[4];
#pragma unroll
        for (int q = 0; q < 4; q++) {
            h[q] = f2bf(f[q]);
            l[q] = f2bf(f[q] - bf2f(h[q]));
        }
        *(ushort4*)&Qh[qidx(r, c4 * 4)] = make_ushort4(h[0], h[1], h[2], h[3]);
        *(ushort4*)&Ql[qidx(r, c4 * 4)] = make_ushort4(l[0], l[1], l[2], l[3]);
    }
    if (tid < BM) { m_s[tid] = -1e30f; l_s[tid] = 0.f; }
    __syncthreads();

    f32x4 Oacc[2][8];
#pragma unroll
    for (int mt = 0; mt < 2; mt++)
#pragma unroll
        for (int nt = 0; nt < 8; nt++)
            Oacc[mt][nt] = (f32x4){0.f, 0.f, 0.f, 0.f};

    const ushort* khp = kh + (size_t)(wave * 16 + l16) * DDIM + lq * 8;
    const ushort* klp = kl + (size_t)(wave * 16 + l16) * DDIM + lq * 8;

    // K prefetch: double-buffered chunks of 4 kc (each kc: 16B hi + 16B lo per lane)
    bf16x8 pfh[2][4], pfl[2][4];
#pragma unroll
    for (int i = 0; i < 4; i++) {
        pfh[0][i] = *(const bf16x8*)(khp + i * 32);
        pfl[0][i] = *(const bf16x8*)(klp + i * 32);
    }

    for (int b = 0; b < NBLK; b++) {
        // ---- QK^T: 3-pass split-bf16, 6 independent accumulator chains ----
        f32x4 s0a = {0,0,0,0}, s0b = {0,0,0,0}, s0c = {0,0,0,0};
        f32x4 s1a = {0,0,0,0}, s1b = {0,0,0,0}, s1c = {0,0,0,0};
#pragma unroll
        for (int c = 0; c < 8; c++) {
            const int nb = (c + 1) & 1, cb = c & 1;
            if (c < 7) {
#pragma unroll
                for (int i = 0; i < 4; i++) {
                    pfh[nb][i] = *(const bf16x8*)(khp + ((c + 1) * 4 + i) * 32);
                    pfl[nb][i] = *(const bf16x8*)(klp + ((c + 1) * 4 + i) * 32);
                }
            } else if (b < NBLK - 1) {
                // chunk0 of next key-block: stays in flight through softmax
#pragma unroll
                for (int i = 0; i < 4; i++) {
                    pfh[0][i] = *(const bf16x8*)(khp + (size_t)BK * DDIM + i * 32);
                    pfl[0][i] = *(const bf16x8*)(klp + (size_t)BK * DDIM + i * 32);
                }
            }
#pragma unroll
            for (int i = 0; i < 4; i++) {
                const int cu = (c * 4 + i) * 32 + lq * 8;
                bf16x8 ah0 = *(const bf16x8*)&Qh[qidx(l16, cu)];
                bf16x8 ah1 = *(const bf16x8*)&Qh[qidx(16 + l16, cu)];
                bf16x8 al0 = *(const bf16x8*)&Ql[qidx(l16, cu)];
                bf16x8 al1 = *(const bf16x8*)&Ql[qidx(16 + l16, cu)];
                s0a = __builtin_amdgcn_mfma_f32_16x16x32_bf16(ah0, pfh[cb][i], s0a, 0, 0, 0);
                s1a = __builtin_amdgcn_mfma_f32_16x16x32_bf16(ah1, pfh[cb][i], s1a, 0, 0, 0);
                s0b = __builtin_amdgcn_mfma_f32_16x16x32_bf16(ah0, pfl[cb][i], s0b, 0, 0, 0);
                s1b = __builtin_amdgcn_mfma_f32_16x16x32_bf16(ah1, pfl[cb][i], s1b, 0, 0, 0);
                s0c = __builtin_amdgcn_mfma_f32_16x16x32_bf16(al0, pfh[cb][i], s0c, 0, 0, 0);
                s1c = __builtin_amdgcn_mfma_f32_16x16x32_bf16(al1, pfh[cb][i], s1c, 0, 0, 0);
            }
        }
        khp += (size_t)BK * DDIM;
        klp += (size_t)BK * DDIM;

        f32x4 s0 = (s0a + s0b) + s0c;
        f32x4 s1 = (s1a + s1b) + s1c;
#pragma unroll
        for (int r = 0; r < 4; r++) {
            Ssc[lq * 4 + r][wave * 16 + l16]      = s0[r];
            Ssc[16 + lq * 4 + r][wave * 16 + l16] = s1[r];
        }
        barrier_lgkm();

        // ---- online softmax: 16 threads per row ----
        {
            int row = tid >> 4;
            int c0  = tid & 15;
            float sv[8];
            float mloc = -1e30f;
#pragma unroll
            for (int j = 0; j < 8; j++) {
                sv[j] = Ssc[row][c0 + 16 * j];
                mloc = fmaxf(mloc, sv[j]);
            }
#pragma unroll
            for (int off = 8; off >= 1; off >>= 1)
                mloc = fmaxf(mloc, __shfl_xor(mloc, off));
            float m_old = m_s[row];
            float m_new = fmaxf(m_old, mloc);
            float psum = 0.f;
#pragma unroll
            for (int j = 0; j < 8; j++) {
                float p = __expf(sv[j] - m_new);
                psum += p;
                Pt[pidx(row, c0 + 16 * j)] = f2bf(p);
            }
#pragma unroll
            for (int off = 8; off >= 1; off >>= 1)
                psum += __shfl_xor(psum, off);
            if (c0 == 0) {
                float sc = __expf(m_old - m_new);
                l_s[row] = l_s[row] * sc + psum;
                m_s[row] = m_new;
                sc_s[row] = sc;
            }
        }
        barrier_lgkm();

        // ---- rescale O, then PV for this wave's d-chunk (2-stage vt pipeline) ----
        float sc0[4], sc1[4];
#pragma unroll
        for (int r = 0; r < 4; r++) {
            sc0[r] = sc_s[lq * 4 + r];
            sc1[r] = sc_s[16 + lq * 4 + r];
        }
#pragma unroll
        for (int nt = 0; nt < 8; nt++)
#pragma unroll
            for (int r = 0; r < 4; r++) {
                Oacc[0][nt][r] *= sc0[r];
                Oacc[1][nt][r] *= sc1[r];
            }

        const ushort* vtb = vt + (size_t)(wave * 128 + l16) * K_KEYS + b * BK + lq * 8;
        bf16x8 vbuf[2][8];
#pragma unroll
        for (int nt = 0; nt < 8; nt++)
            vbuf[0][nt] = *(const bf16x8*)(vtb + (size_t)nt * 16 * K_KEYS);
#pragma unroll
        for (int kc = 0; kc < 4; kc++) {
            if (kc < 3) {
#pragma unroll
                for (int nt = 0; nt < 8; nt++)
                    vbuf[(kc + 1) & 1][nt] = *(const bf16x8*)(vtb + (size_t)nt * 16 * K_KEYS + (kc + 1) * 32);
            }
            bf16x8 pa0 = *(const bf16x8*)&Pt[pidx(l16, kc * 32 + lq * 8)];
            bf16x8 pa1 = *(const bf16x8*)&Pt[pidx(16 + l16, kc * 32 + lq * 8)];
#pragma unroll
            for (int nt = 0; nt < 8; nt++) {
                Oacc[0][nt] = __builtin_amdgcn_mfma_f32_16x16x32_bf16(pa0, vbuf[kc & 1][nt], Oacc[0][nt], 0, 0, 0);
                Oacc[1][nt] = __builtin_amdgcn_mfma_f32_16x16x32_bf16(pa1, vbuf[kc & 1][nt], Oacc[1][nt], 0, 0, 0);
            }
        }
        // Pt/Ssc reuse ordered by the post-QK barrier of the next iteration
    }

    // ---- epilogue: normalize by l and store ----
    float li0[4], li1[4];
#pragma unroll
    for (int r = 0; r < 4; r++) {
        li0[r] = 1.f / l_s[lq * 4 + r];
        li1[r] = 1.f / l_s[16 + lq * 4 + r];
    }
#pragma unroll
    for (int nt = 0; nt < 8; nt++) {
#pragma unroll
        for (int r = 0; r < 4; r++) {
            int col = wave * 128 + nt * 16 + l16;
            int rowA = row0 + lq * 4 + r;
            out[(size_t)rowA * DDIM + col]        = Oacc[0][nt][r] * li0[r];
            out[(size_t)(rowA + 16) * DDIM + col] = Oacc[1][nt][r] * li1[r];
        }
    }
}

extern "C" void kernel_launch(void* const* d_in, const int* in_sizes, int n_in,
                              void* d_out, int out_size, void* d_ws, size_t ws_size,
                              hipStream_t stream) {
    const float* z    = (const float*)d_in[0];
    const float* keys = (const float*)d_in[1];
    const float* vals = (const float*)d_in[2];
    float* outp = (float*)d_out;

    ushort* kh  = (ushort*)d_ws;                       // 8 MB
    ushort* kl  = kh + (size_t)K_KEYS * DDIM;          // 8 MB
    ushort* vtw = kl + (size_t)K_KEYS * DDIM;          // 8 MB

    prep_split<<<2048, 256, 0, stream>>>(keys, kh, kl);
    prep_vt<<<dim3(K_KEYS / 32, DDIM / 32), dim3(32, 8), 0, stream>>>(vals, vtw);
    attn_main<<<N_ROWS / BM, 512, 0, stream>>>(z, kh, kl, vtw, outp);
}

// Round 3
// 1405.087 us; speedup vs baseline: 2.1155x; 2.1155x over previous
//
#include <hip/hip_runtime.h>
#include <hip/hip_bf16.h>

typedef __attribute__((ext_vector_type(8))) short bf16x8;
typedef __attribute__((ext_vector_type(4))) float f32x4;

#define N_ROWS 32768
#define K_KEYS 4096
#define DDIM   1024
#define BM 32
#define BK 128
#define NBLK (K_KEYS / BK)   /* 32 */
#define SP 132               /* Sx fp32 pitch: 2-way-free writes */

__device__ __forceinline__ ushort f2bf(float f) {
    __hip_bfloat16 b = __float2bfloat16(f);
    return *(ushort*)&b;
}
__device__ __forceinline__ float bf2f(ushort u) {
    __hip_bfloat16 b = *(__hip_bfloat16*)&u;
    return __bfloat162float(b);
}

// Pt swizzle (ushort units, 8-ushort granule XORed with row&7)
__device__ __forceinline__ int pidx(int r, int c_us) { return r * 128 + (c_us ^ ((r & 7) << 3)); }

// barrier that does NOT drain vmcnt: global prefetches stay in flight.
// All cross-wave deps inside the loop are LDS-only.
__device__ __forceinline__ void barrier_lgkm() {
    asm volatile("s_waitcnt lgkmcnt(0)" ::: "memory");
    __builtin_amdgcn_s_barrier();
    asm volatile("" ::: "memory");
}

// keys fp32 -> packed MFMA-fragment tiles, hi/lo split.
// Tile (g,kc): 16 keys x 32 dims = 64 lanes x 16B contiguous (1KB).
// element (k,d): g=k>>4, l16=k&15, kc=d>>5, lq=(d>>3)&3, e=d&7
// dst = (g*32+kc)*512 + (lq*16+l16)*8 + e
__global__ void prep_split(const float* __restrict__ src,
                           ushort* __restrict__ hi,
                           ushort* __restrict__ lo) {
    int idx  = blockIdx.x * 256 + threadIdx.x;   // 0..524287
    int lane = idx & 63, tile = idx >> 6;        // tile = g*32+kc
    int g = tile >> 5, kc = tile & 31;
    int l16 = lane & 15, lq = lane >> 4;
    int k = g * 16 + l16, d = kc * 32 + lq * 8;
    const float* s = src + (size_t)k * DDIM + d;
    float4 a = ((const float4*)s)[0];
    float4 c = ((const float4*)s)[1];
    float f[8] = {a.x, a.y, a.z, a.w, c.x, c.y, c.z, c.w};
    bf16x8 h, l;
#pragma unroll
    for (int j = 0; j < 8; j++) {
        ushort hh = f2bf(f[j]);
        h[j] = (short)hh;
        l[j] = (short)f2bf(f[j] - bf2f(hh));
    }
    *(bf16x8*)(hi + (size_t)tile * 512 + lane * 8) = h;
    *(bf16x8*)(lo + (size_t)tile * 512 + lane * 8) = l;
}

// values fp32 [K][D] -> packed V^T fragment tiles.
// Tile (dg,kt): 16 dims x 32 keys, lane=lq*16+l16: d=dg*16+l16, k=kt*32+lq*8+e
// dst = (dg*128+kt)*512 + lane*8 + e
__global__ void prep_vt(const float* __restrict__ v, ushort* __restrict__ vt) {
    __shared__ float t[32][33];
    const int tk = blockIdx.x;            // key tile 0..127
    const int td = blockIdx.y;            // 32-dim tile 0..31
    const int tx = threadIdx.x & 31;
    const int ty = threadIdx.x >> 5;      // 0..7
#pragma unroll
    for (int r = 0; r < 4; r++) {
        int k = tk * 32 + ty + 8 * r;
        t[ty + 8 * r][tx] = v[(size_t)k * DDIM + td * 32 + tx];
    }
    __syncthreads();
    if (threadIdx.x < 128) {
        int s    = threadIdx.x >> 6;      // 0/1: which 16-dim half
        int lane = threadIdx.x & 63;
        int l16  = lane & 15, lq = lane >> 4;
        int dg   = td * 2 + s;
        int dl   = s * 16 + l16;
        bf16x8 o;
#pragma unroll
        for (int e = 0; e < 8; e++)
            o[e] = (short)f2bf(t[lq * 8 + e][dl]);
        *(bf16x8*)(vt + ((size_t)dg * 128 + tk) * 512 + lane * 8) = o;
    }
}

// Fused flash kernel, d-split QK:
//  - wave w owns dims [128w,128w+128): Q hi/lo frags live in 64 VGPRs for
//    the whole kernel; K streams global->reg (packed tiles, double-buffered).
//  - partial S exchanged via LDS, softmax reduces 8 partials, P -> Pt (dbuf).
//  - PV: wave w owns output d-chunk [128w,128w+128), vt packed tiles.
__launch_bounds__(512, 2)
__global__ void attn_main(const float* __restrict__ z,
                          const ushort* __restrict__ khp,
                          const ushort* __restrict__ klp,
                          const ushort* __restrict__ vtp,
                          float* __restrict__ out) {
    __shared__ float  Sx[8][BM][SP];      // 135168 B
    __shared__ ushort Pt2[2][BM * 128];   // 16384 B
    __shared__ float  m_s[BM], l_s[BM], sc_s[BM];

    const int tid  = threadIdx.x;
    const int wave = tid >> 6;
    const int lane = tid & 63;
    const int l16  = lane & 15;
    const int lq   = lane >> 4;           // 0..3
    const int row0 = blockIdx.x * BM;

    // ---- Q hi/lo fragments for this wave's d-slice, in registers ----
    bf16x8 qh[2][4], ql[2][4];
#pragma unroll
    for (int rg = 0; rg < 2; rg++)
#pragma unroll
        for (int i = 0; i < 4; i++) {
            int d0  = (wave * 4 + i) * 32 + lq * 8;
            int row = row0 + rg * 16 + l16;
            float4 a = *(const float4*)(z + (size_t)row * DDIM + d0);
            float4 c = *(const float4*)(z + (size_t)row * DDIM + d0 + 4);
            float f[8] = {a.x, a.y, a.z, a.w, c.x, c.y, c.z, c.w};
            bf16x8 h, l;
#pragma unroll
            for (int e = 0; e < 8; e++) {
                ushort hh = f2bf(f[e]);
                h[e] = (short)hh;
                l[e] = (short)f2bf(f[e] - bf2f(hh));
            }
            qh[rg][i] = h;
            ql[rg][i] = l;
        }
    if (tid < BM) { m_s[tid] = -1e30f; l_s[tid] = 0.f; }

    f32x4 Oacc[2][8];
#pragma unroll
    for (int mt = 0; mt < 2; mt++)
#pragma unroll
        for (int nt = 0; nt < 8; nt++)
            Oacc[mt][nt] = (f32x4){0.f, 0.f, 0.f, 0.f};

    // K tile addressing (ushort units):
    //   frag(b,g,i) = khp + b*131072 + g*16384 + wave*2048 + i*512 + lane*8
    const ushort* khB = khp + wave * 2048 + lane * 8;
    const ushort* klB = klp + wave * 2048 + lane * 8;
    // vt addressing: frag(b,nt,kc) = vtp + wave*524288 + nt*65536 + b*2048 + kc*512 + lane*8
    const ushort* vtB = vtp + (size_t)wave * 524288 + lane * 8;

    bf16x8 KbH[2][2], KbL[2][2];   // [buf][gpair member]
#define LOADK(bb, gg, ii, buf)                                                              \
    do {                                                                                    \
        const ushort* _ph = khB + (size_t)(bb) * 131072 + (gg) * 16384 + (ii) * 512;        \
        const ushort* _pl = klB + (size_t)(bb) * 131072 + (gg) * 16384 + (ii) * 512;        \
        KbH[buf][0] = *(const bf16x8*)_ph;                                                  \
        KbH[buf][1] = *(const bf16x8*)(_ph + 16384);                                        \
        KbL[buf][0] = *(const bf16x8*)_pl;                                                  \
        KbL[buf][1] = *(const bf16x8*)(_pl + 16384);                                        \
    } while (0)

    LOADK(0, 0, 0, 0);

    for (int b = 0; b < NBLK; b++) {
        // ---- QK^T partials over this wave's 128 dims, all 128 keys ----
        f32x4 sA0, sA1, sB0, sB1;
#pragma unroll
        for (int s = 0; s < 16; s++) {
            const int gp = s >> 2, i = s & 3;
            const int cb = s & 1, nb2 = cb ^ 1;
            if (s < 15) {
                const int sn = s + 1;
                LOADK(b, (sn >> 2) * 2, sn & 3, nb2);
            } else {
                int bn = (b + 1 < NBLK) ? b + 1 : b;
                LOADK(bn, 0, 0, nb2);
            }
            if (i == 0) {
                sA0 = (f32x4){0,0,0,0}; sA1 = (f32x4){0,0,0,0};
                sB0 = (f32x4){0,0,0,0}; sB1 = (f32x4){0,0,0,0};
            }
            sA0 = __builtin_amdgcn_mfma_f32_16x16x32_bf16(qh[0][i], KbH[cb][0], sA0, 0, 0, 0);
            sA1 = __builtin_amdgcn_mfma_f32_16x16x32_bf16(qh[1][i], KbH[cb][0], sA1, 0, 0, 0);
            sB0 = __builtin_amdgcn_mfma_f32_16x16x32_bf16(qh[0][i], KbH[cb][1], sB0, 0, 0, 0);
            sB1 = __builtin_amdgcn_mfma_f32_16x16x32_bf16(qh[1][i], KbH[cb][1], sB1, 0, 0, 0);
            sA0 = __builtin_amdgcn_mfma_f32_16x16x32_bf16(qh[0][i], KbL[cb][0], sA0, 0, 0, 0);
            sA1 = __builtin_amdgcn_mfma_f32_16x16x32_bf16(qh[1][i], KbL[cb][0], sA1, 0, 0, 0);
            sB0 = __builtin_amdgcn_mfma_f32_16x16x32_bf16(qh[0][i], KbL[cb][1], sB0, 0, 0, 0);
            sB1 = __builtin_amdgcn_mfma_f32_16x16x32_bf16(qh[1][i], KbL[cb][1], sB1, 0, 0, 0);
            sA0 = __builtin_amdgcn_mfma_f32_16x16x32_bf16(ql[0][i], KbH[cb][0], sA0, 0, 0, 0);
            sA1 = __builtin_amdgcn_mfma_f32_16x16x32_bf16(ql[1][i], KbH[cb][0], sA1, 0, 0, 0);
            sB0 = __builtin_amdgcn_mfma_f32_16x16x32_bf16(ql[0][i], KbH[cb][1], sB0, 0, 0, 0);
            sB1 = __builtin_amdgcn_mfma_f32_16x16x32_bf16(ql[1][i], KbH[cb][1], sB1, 0, 0, 0);
            if (i == 3) {
                const int cA = (2 * gp) * 16 + l16, cB = cA + 16;
#pragma unroll
                for (int r = 0; r < 4; r++) {
                    Sx[wave][lq * 4 + r][cA]      = sA0[r];
                    Sx[wave][16 + lq * 4 + r][cA] = sA1[r];
                    Sx[wave][lq * 4 + r][cB]      = sB0[r];
                    Sx[wave][16 + lq * 4 + r][cB] = sB1[r];
                }
            }
        }

        // vt kc=0 prefetch: issue before the softmax barriers, lands during softmax
        bf16x8 vbuf[2][8];
        const ushort* vtI = vtB + (size_t)b * 2048;
#pragma unroll
        for (int nt = 0; nt < 8; nt++)
            vbuf[0][nt] = *(const bf16x8*)(vtI + nt * 65536);

        barrier_lgkm();

        // ---- softmax: thread (row, c0) owns cols [8c0, 8c0+8), reduces 8 partials ----
        {
            const int row = tid >> 4;
            const int c0  = tid & 15;
            f32x4 a0 = {0,0,0,0}, a1 = {0,0,0,0};
#pragma unroll
            for (int w = 0; w < 8; w++) {
                a0 += *(const f32x4*)&Sx[w][row][8 * c0];
                a1 += *(const f32x4*)&Sx[w][row][8 * c0 + 4];
            }
            float sv[8] = {a0[0], a0[1], a0[2], a0[3], a1[0], a1[1], a1[2], a1[3]};
            float mloc = sv[0];
#pragma unroll
            for (int j = 1; j < 8; j++) mloc = fmaxf(mloc, sv[j]);
#pragma unroll
            for (int off = 8; off >= 1; off >>= 1)
                mloc = fmaxf(mloc, __shfl_xor(mloc, off));
            float m_old = m_s[row];
            float m_new = fmaxf(m_old, mloc);
            float psum = 0.f;
            bf16x8 pb;
#pragma unroll
            for (int j = 0; j < 8; j++) {
                float p = __expf(sv[j] - m_new);
                psum += p;
                pb[j] = (short)f2bf(p);
            }
            *(bf16x8*)&Pt2[b & 1][pidx(row, 8 * c0)] = pb;
#pragma unroll
            for (int off = 8; off >= 1; off >>= 1)
                psum += __shfl_xor(psum, off);
            if (c0 == 0) {
                float sc = __expf(m_old - m_new);
                l_s[row] = l_s[row] * sc + psum;
                m_s[row] = m_new;
                sc_s[row] = sc;
            }
        }
        barrier_lgkm();

        // ---- rescale O, then PV over this key-block ----
        float sc0[4], sc1[4];
#pragma unroll
        for (int r = 0; r < 4; r++) {
            sc0[r] = sc_s[lq * 4 + r];
            sc1[r] = sc_s[16 + lq * 4 + r];
        }
#pragma unroll
        for (int nt = 0; nt < 8; nt++)
#pragma unroll
            for (int r = 0; r < 4; r++) {
                Oacc[0][nt][r] *= sc0[r];
                Oacc[1][nt][r] *= sc1[r];
            }

        const ushort* PtC = &Pt2[b & 1][0];
#pragma unroll
        for (int kc = 0; kc < 4; kc++) {
            if (kc < 3) {
#pragma unroll
                for (int nt = 0; nt < 8; nt++)
                    vbuf[(kc + 1) & 1][nt] = *(const bf16x8*)(vtI + nt * 65536 + (kc + 1) * 512);
            }
            bf16x8 pa0 = *(const bf16x8*)&PtC[pidx(l16, kc * 32 + lq * 8)];
            bf16x8 pa1 = *(const bf16x8*)&PtC[pidx(16 + l16, kc * 32 + lq * 8)];
#pragma unroll
            for (int nt = 0; nt < 8; nt++) {
                Oacc[0][nt] = __builtin_amdgcn_mfma_f32_16x16x32_bf16(pa0, vbuf[kc & 1][nt], Oacc[0][nt], 0, 0, 0);
                Oacc[1][nt] = __builtin_amdgcn_mfma_f32_16x16x32_bf16(pa1, vbuf[kc & 1][nt], Oacc[1][nt], 0, 0, 0);
            }
        }
    }
    __syncthreads();

    // ---- epilogue: normalize by l and store ----
    float li0[4], li1[4];
#pragma unroll
    for (int r = 0; r < 4; r++) {
        li0[r] = 1.f / l_s[lq * 4 + r];
        li1[r] = 1.f / l_s[16 + lq * 4 + r];
    }
#pragma unroll
    for (int nt = 0; nt < 8; nt++) {
#pragma unroll
        for (int r = 0; r < 4; r++) {
            int col = wave * 128 + nt * 16 + l16;
            int rowA = row0 + lq * 4 + r;
            out[(size_t)rowA * DDIM + col]        = Oacc[0][nt][r] * li0[r];
            out[(size_t)(rowA + 16) * DDIM + col] = Oacc[1][nt][r] * li1[r];
        }
    }
}

extern "C" void kernel_launch(void* const* d_in, const int* in_sizes, int n_in,
                              void* d_out, int out_size, void* d_ws, size_t ws_size,
                              hipStream_t stream) {
    const float* z    = (const float*)d_in[0];
    const float* keys = (const float*)d_in[1];
    const float* vals = (const float*)d_in[2];
    float* outp = (float*)d_out;

    ushort* kh  = (ushort*)d_ws;                       // 8 MB packed hi tiles
    ushort* kl  = kh + (size_t)K_KEYS * DDIM;          // 8 MB packed lo tiles
    ushort* vtw = kl + (size_t)K_KEYS * DDIM;          // 8 MB packed vt tiles

    prep_split<<<2048, 256, 0, stream>>>(keys, kh, kl);
    prep_vt<<<dim3(K_KEYS / 32, DDIM / 32), 256, 0, stream>>>(vals, vtw);
    attn_main<<<N_ROWS / BM, 512, 0, stream>>>(z, kh, kl, vtw, outp);
}

// Round 5
// 1158.454 us; speedup vs baseline: 2.5659x; 1.2129x over previous
//
#include <hip/hip_runtime.h>
#include <hip/hip_bf16.h>

typedef __attribute__((ext_vector_type(8))) short bf16x8;
typedef __attribute__((ext_vector_type(4))) float f32x4;
typedef __attribute__((ext_vector_type(4))) int   i32x4;
typedef signed char i8;

#define N_ROWS 32768
#define K_KEYS 4096
#define DDIM   1024
#define BM 32
#define BK 128
#define NBLK (K_KEYS / BK)   /* 32 */
#define SP 132               /* Sx fp32 pitch */
#define SC1 (0.00390625f)        /* 2^-8  */
#define SC2 (1.52587890625e-05f) /* 2^-16 */

__device__ __forceinline__ ushort f2bf(float f) {
    __hip_bfloat16 b = __float2bfloat16(f);
    return *(ushort*)&b;
}
__device__ __forceinline__ float bf2f(ushort u) {
    __hip_bfloat16 b = *(__hip_bfloat16*)&u;
    return __bfloat162float(b);
}
__device__ __forceinline__ int clampi(int x) { return x > 127 ? 127 : (x < -127 ? -127 : x); }

// Pt swizzle (ushort units, 8-ushort granule XORed with row&7)
__device__ __forceinline__ int pidx(int r, int c_us) { return r * 128 + (c_us ^ ((r & 7) << 3)); }

// barrier that does NOT drain vmcnt: global prefetches stay in flight.
__device__ __forceinline__ void barrier_lgkm() {
    asm volatile("s_waitcnt lgkmcnt(0)" ::: "memory");
    __builtin_amdgcn_s_barrier();
    asm volatile("" ::: "memory");
}

// ---- prep: keys -> stream A (P1 operand): KH int8, tiles (g,c)=16 keys x 64 dims ----
// B-frag layout: lane l: key=g*16+(l&15), dims c*64+(l>>4)*16+e, e=byte 0..15
__global__ void prep_ka(const float* __restrict__ keys, i8* __restrict__ sa) {
    int idx  = blockIdx.x * 256 + threadIdx.x;   // 0..262143
    int lane = idx & 63, tile = idx >> 6;        // tile = g*16 + c
    int g = tile >> 4, c = tile & 15;
    int key = g * 16 + (lane & 15);
    int d0  = c * 64 + (lane >> 4) * 16;
    const float* s = keys + (size_t)key * DDIM + d0;
    union { i32x4 v; i8 b[16]; } u;
#pragma unroll
    for (int e = 0; e < 16; e++)
        u.b[e] = (i8)clampi((int)rintf(s[e] * 16.f));
    *(i32x4*)(sa + (size_t)tile * 1024 + lane * 16) = u.v;
}

// ---- prep: keys -> stream B (M2 operand): [KL,KH] interleaved, tiles (g,m)=16 keys x 32 dims ----
// A-side even byte holds QH -> B even byte must hold KL (cross term QH*KL);
// A-side odd byte holds QL -> B odd byte holds KH (cross term QL*KH).
__global__ void prep_kb(const float* __restrict__ keys, i8* __restrict__ sb) {
    int idx  = blockIdx.x * 256 + threadIdx.x;   // 0..524287
    int lane = idx & 63, tile = idx >> 6;        // tile = g*32 + m
    int g = tile >> 5, m = tile & 31;
    int key = g * 16 + (lane & 15);
    int d0  = m * 32 + (lane >> 4) * 8;
    const float* s = keys + (size_t)key * DDIM + d0;
    union { i32x4 v; i8 b[16]; } u;
#pragma unroll
    for (int e = 0; e < 8; e++) {
        float q = s[e];
        int h = clampi((int)rintf(q * 16.f));
        int l = clampi((int)rintf((q - (float)h * 0.0625f) * 4096.f));
        u.b[2 * e]     = (i8)l;   // KL pairs with QH
        u.b[2 * e + 1] = (i8)h;   // KH pairs with QL
    }
    *(i32x4*)(sb + (size_t)tile * 1024 + lane * 16) = u.v;
}

// ---- prep: values fp32 [K][D] -> packed V^T bf16 fragment tiles (unchanged) ----
__global__ void prep_vt(const float* __restrict__ v, ushort* __restrict__ vt) {
    __shared__ float t[32][33];
    const int tk = blockIdx.x;
    const int td = blockIdx.y;
    const int tx = threadIdx.x & 31;
    const int ty = threadIdx.x >> 5;
#pragma unroll
    for (int r = 0; r < 4; r++) {
        int k = tk * 32 + ty + 8 * r;
        t[ty + 8 * r][tx] = v[(size_t)k * DDIM + td * 32 + tx];
    }
    __syncthreads();
    if (threadIdx.x < 128) {
        int s    = threadIdx.x >> 6;
        int lane = threadIdx.x & 63;
        int l16  = lane & 15, lq = lane >> 4;
        int dg   = td * 2 + s;
        int dl   = s * 16 + l16;
        bf16x8 o;
#pragma unroll
        for (int e = 0; e < 8; e++)
            o[e] = (short)f2bf(t[lq * 8 + e][dl]);
        *(bf16x8*)(vt + ((size_t)dg * 128 + tk) * 512 + lane * 8) = o;
    }
}

// Fused flash kernel, d-split QK with int8 exact-split MFMA.
__launch_bounds__(512, 2)
__global__ void attn_main(const float* __restrict__ z,
                          const i8* __restrict__ sa,
                          const i8* __restrict__ sb,
                          const ushort* __restrict__ vtp,
                          float* __restrict__ out) {
    __shared__ float  Sx[8][BM][SP];      // 135168 B
    __shared__ ushort Pt2[2][BM * 128];   // 16384 B
    __shared__ float  m_s[BM], l_s[BM], sc_s[BM];

    const int tid  = threadIdx.x;
    const int wave = tid >> 6;
    const int lane = tid & 63;
    const int l16  = lane & 15;
    const int lq   = lane >> 4;
    const int row0 = blockIdx.x * BM;

    // ---- Q int8-split fragments for this wave's 128 dims, in registers ----
    // P1 A-frags: qP1[rg][c]: dims wave*128 + c*64 + lq*16 + e (QH)
    // M2 A-frags: qM2[rg][m]: dims wave*128 + m*32 + lq*8 + (e>>1), bytes [QH,QL]
    i32x4 qP1[2][2], qM2[2][4];
#pragma unroll
    for (int rg = 0; rg < 2; rg++) {
        int row = row0 + rg * 16 + l16;
        const float* zr = z + (size_t)row * DDIM + wave * 128;
#pragma unroll
        for (int c = 0; c < 2; c++) {
            union { i32x4 v; i8 b[16]; } u;
            const float* s = zr + c * 64 + lq * 16;
#pragma unroll
            for (int e = 0; e < 16; e++)
                u.b[e] = (i8)clampi((int)rintf(s[e] * 16.f));
            qP1[rg][c] = u.v;
        }
#pragma unroll
        for (int m = 0; m < 4; m++) {
            union { i32x4 v; i8 b[16]; } u;
            const float* s = zr + m * 32 + lq * 8;
#pragma unroll
            for (int e = 0; e < 8; e++) {
                float q = s[e];
                int h = clampi((int)rintf(q * 16.f));
                int l = clampi((int)rintf((q - (float)h * 0.0625f) * 4096.f));
                u.b[2 * e]     = (i8)h;   // QH pairs with KL
                u.b[2 * e + 1] = (i8)l;   // QL pairs with KH
            }
            qM2[rg][m] = u.v;
        }
    }
    if (tid < BM) { m_s[tid] = -1e30f; l_s[tid] = 0.f; }

    f32x4 Oacc[2][8];
#pragma unroll
    for (int mt = 0; mt < 2; mt++)
#pragma unroll
        for (int nt = 0; nt < 8; nt++)
            Oacc[mt][nt] = (f32x4){0.f, 0.f, 0.f, 0.f};

    // K stream bases (this wave's c/m slices), lane offset folded in
    const i8* saB = sa + (size_t)wave * 2048 + lane * 16;   // + g*16384 (+1024 for c+1)
    const i8* sbB = sb + (size_t)wave * 4096 + lane * 16;   // + g*32768 + j*1024
    const ushort* vtB = vtp + (size_t)wave * 524288 + lane * 8;

    i32x4 kA[2][2], kB[2][4];
#define LOADK8(gg, buf)                                                        \
    do {                                                                       \
        const i8* _a = saB + (size_t)(gg) * 16384;                             \
        const i8* _b = sbB + (size_t)(gg) * 32768;                             \
        kA[buf][0] = *(const i32x4*)_a;                                        \
        kA[buf][1] = *(const i32x4*)(_a + 1024);                               \
        kB[buf][0] = *(const i32x4*)_b;                                        \
        kB[buf][1] = *(const i32x4*)(_b + 1024);                               \
        kB[buf][2] = *(const i32x4*)(_b + 2048);                               \
        kB[buf][3] = *(const i32x4*)(_b + 3072);                               \
    } while (0)

    LOADK8(0, 0);

    for (int b = 0; b < NBLK; b++) {
        // ---- QK^T: per key-tile gt (16 keys), 12 int8 MFMAs over 128 dims ----
#pragma unroll
        for (int gt = 0; gt < 8; gt++) {
            const int cb = gt & 1, nb2 = cb ^ 1;
            if (gt < 7) {
                LOADK8(8 * b + gt + 1, nb2);
            } else {
                int gn = (b + 1 < NBLK) ? 8 * (b + 1) : 8 * b;
                LOADK8(gn, nb2);
            }
            i32x4 p1a = {0,0,0,0}, p1b = {0,0,0,0};
            i32x4 m2a0 = {0,0,0,0}, m2a1 = {0,0,0,0};
            i32x4 m2b0 = {0,0,0,0}, m2b1 = {0,0,0,0};
            p1a  = __builtin_amdgcn_mfma_i32_16x16x64_i8(qP1[0][0], kA[cb][0], p1a, 0, 0, 0);
            p1b  = __builtin_amdgcn_mfma_i32_16x16x64_i8(qP1[1][0], kA[cb][0], p1b, 0, 0, 0);
            m2a0 = __builtin_amdgcn_mfma_i32_16x16x64_i8(qM2[0][0], kB[cb][0], m2a0, 0, 0, 0);
            m2a1 = __builtin_amdgcn_mfma_i32_16x16x64_i8(qM2[1][0], kB[cb][0], m2a1, 0, 0, 0);
            m2b0 = __builtin_amdgcn_mfma_i32_16x16x64_i8(qM2[0][1], kB[cb][1], m2b0, 0, 0, 0);
            m2b1 = __builtin_amdgcn_mfma_i32_16x16x64_i8(qM2[1][1], kB[cb][1], m2b1, 0, 0, 0);
            p1a  = __builtin_amdgcn_mfma_i32_16x16x64_i8(qP1[0][1], kA[cb][1], p1a, 0, 0, 0);
            p1b  = __builtin_amdgcn_mfma_i32_16x16x64_i8(qP1[1][1], kA[cb][1], p1b, 0, 0, 0);
            m2a0 = __builtin_amdgcn_mfma_i32_16x16x64_i8(qM2[0][2], kB[cb][2], m2a0, 0, 0, 0);
            m2a1 = __builtin_amdgcn_mfma_i32_16x16x64_i8(qM2[1][2], kB[cb][2], m2a1, 0, 0, 0);
            m2b0 = __builtin_amdgcn_mfma_i32_16x16x64_i8(qM2[0][3], kB[cb][3], m2b0, 0, 0, 0);
            m2b1 = __builtin_amdgcn_mfma_i32_16x16x64_i8(qM2[1][3], kB[cb][3], m2b1, 0, 0, 0);

            const int col = gt * 16 + l16;
#pragma unroll
            for (int r = 0; r < 4; r++) {
                Sx[wave][lq * 4 + r][col] =
                    fmaf((float)p1a[r], SC1, ((float)m2a0[r] + (float)m2b0[r]) * SC2);
                Sx[wave][16 + lq * 4 + r][col] =
                    fmaf((float)p1b[r], SC1, ((float)m2a1[r] + (float)m2b1[r]) * SC2);
            }
        }

        // vt kc=0 prefetch: lands during softmax
        bf16x8 vbuf[2][8];
        const ushort* vtI = vtB + (size_t)b * 2048;
#pragma unroll
        for (int nt = 0; nt < 8; nt++)
            vbuf[0][nt] = *(const bf16x8*)(vtI + nt * 65536);

        barrier_lgkm();

        // ---- softmax: thread (row, c0) owns cols [8c0, 8c0+8), reduces 8 partials ----
        {
            const int row = tid >> 4;
            const int c0  = tid & 15;
            f32x4 a0 = {0,0,0,0}, a1 = {0,0,0,0};
#pragma unroll
            for (int w = 0; w < 8; w++) {
                a0 += *(const f32x4*)&Sx[w][row][8 * c0];
                a1 += *(const f32x4*)&Sx[w][row][8 * c0 + 4];
            }
            float sv[8] = {a0[0], a0[1], a0[2], a0[3], a1[0], a1[1], a1[2], a1[3]};
            float mloc = sv[0];
#pragma unroll
            for (int j = 1; j < 8; j++) mloc = fmaxf(mloc, sv[j]);
#pragma unroll
            for (int off = 8; off >= 1; off >>= 1)
                mloc = fmaxf(mloc, __shfl_xor(mloc, off));
            float m_old = m_s[row];
            float m_new = fmaxf(m_old, mloc);
            float psum = 0.f;
            bf16x8 pb;
#pragma unroll
            for (int j = 0; j < 8; j++) {
                float p = __expf(sv[j] - m_new);
                psum += p;
                pb[j] = (short)f2bf(p);
            }
            *(bf16x8*)&Pt2[b & 1][pidx(row, 8 * c0)] = pb;
#pragma unroll
            for (int off = 8; off >= 1; off >>= 1)
                psum += __shfl_xor(psum, off);
            if (c0 == 0) {
                float sc = __expf(m_old - m_new);
                l_s[row] = l_s[row] * sc + psum;
                m_s[row] = m_new;
                sc_s[row] = sc;
            }
        }
        barrier_lgkm();

        // ---- rescale O, then PV over this key-block ----
        float sc0[4], sc1[4];
#pragma unroll
        for (int r = 0; r < 4; r++) {
            sc0[r] = sc_s[lq * 4 + r];
            sc1[r] = sc_s[16 + lq * 4 + r];
        }
#pragma unroll
        for (int nt = 0; nt < 8; nt++)
#pragma unroll
            for (int r = 0; r < 4; r++) {
                Oacc[0][nt][r] *= sc0[r];
                Oacc[1][nt][r] *= sc1[r];
            }

        const ushort* PtC = &Pt2[b & 1][0];
#pragma unroll
        for (int kc = 0; kc < 4; kc++) {
            if (kc < 3) {
#pragma unroll
                for (int nt = 0; nt < 8; nt++)
                    vbuf[(kc + 1) & 1][nt] = *(const bf16x8*)(vtI + nt * 65536 + (kc + 1) * 512);
            }
            bf16x8 pa0 = *(const bf16x8*)&PtC[pidx(l16, kc * 32 + lq * 8)];
            bf16x8 pa1 = *(const bf16x8*)&PtC[pidx(16 + l16, kc * 32 + lq * 8)];
#pragma unroll
            for (int nt = 0; nt < 8; nt++) {
                Oacc[0][nt] = __builtin_amdgcn_mfma_f32_16x16x32_bf16(pa0, vbuf[kc & 1][nt], Oacc[0][nt], 0, 0, 0);
                Oacc[1][nt] = __builtin_amdgcn_mfma_f32_16x16x32_bf16(pa1, vbuf[kc & 1][nt], Oacc[1][nt], 0, 0, 0);
            }
        }
    }
    __syncthreads();

    // ---- epilogue: normalize by l and store ----
    float li0[4], li1[4];
#pragma unroll
    for (int r = 0; r < 4; r++) {
        li0[r] = 1.f / l_s[lq * 4 + r];
        li1[r] = 1.f / l_s[16 + lq * 4 + r];
    }
#pragma unroll
    for (int nt = 0; nt < 8; nt++) {
#pragma unroll
        for (int r = 0; r < 4; r++) {
            int col = wave * 128 + nt * 16 + l16;
            int rowA = row0 + lq * 4 + r;
            out[(size_t)rowA * DDIM + col]        = Oacc[0][nt][r] * li0[r];
            out[(size_t)(rowA + 16) * DDIM + col] = Oacc[1][nt][r] * li1[r];
        }
    }
}

extern "C" void kernel_launch(void* const* d_in, const int* in_sizes, int n_in,
                              void* d_out, int out_size, void* d_ws, size_t ws_size,
                              hipStream_t stream) {
    const float* z    = (const float*)d_in[0];
    const float* keys = (const float*)d_in[1];
    const float* vals = (const float*)d_in[2];
    float* outp = (float*)d_out;

    i8* sa = (i8*)d_ws;                                   // 4 MB (P1 KH tiles)
    i8* sb = sa + (size_t)4 * 1024 * 1024;                // 8 MB (M2 [KL,KH] tiles)
    ushort* vtw = (ushort*)(sb + (size_t)8 * 1024 * 1024); // 8 MB (V^T bf16 tiles)

    prep_ka<<<1024, 256, 0, stream>>>(keys, sa);
    prep_kb<<<2048, 256, 0, stream>>>(keys, sb);
    prep_vt<<<dim3(K_KEYS / 32, DDIM / 32), 256, 0, stream>>>(vals, vtw);
    attn_main<<<N_ROWS / BM, 512, 0, stream>>>(z, sa, sb, vtw, outp);
}